// Round 5
// baseline (295.068 us; speedup 1.0000x reference)
//
#include <hip/hip_runtime.h>

#define DIM 64
#define NHEADS 8
#define NPOS 2048
#define PADW 3

typedef float f32x4 __attribute__((ext_vector_type(4)));

// Taylor coefficients 1/j!
#define C1 1.0f
#define C2 0.5f
#define C3 (1.0f / 6.0f)
#define C4 (1.0f / 24.0f)
#define C5 (1.0f / 120.0f)
#define C6 (1.0f / 720.0f)
#define C7 (1.0f / 5040.0f)
#define C8 (1.0f / 40320.0f)

__device__ __forceinline__ f32x4 ld4(const float* p) { return *reinterpret_cast<const f32x4*>(p); }
__device__ __forceinline__ void st4(float* p, f32x4 v) { *reinterpret_cast<f32x4*>(p) = v; }
__device__ __forceinline__ void tzero(float (&a)[4][4]) {
#pragma unroll
  for (int i = 0; i < 4; ++i)
#pragma unroll
    for (int j = 0; j < 4; ++j) a[i][j] = 0.0f;
}
__device__ __forceinline__ void tfma(float (&a)[4][4], const f32x4 x, const f32x4 y) {
#pragma unroll
  for (int i = 0; i < 4; ++i)
#pragma unroll
    for (int j = 0; j < 4; ++j) a[i][j] = fmaf(x[i], y[j], a[i][j]);
}

// ---- Compile-time position->source grouping ----------------------------------
// Tree structure: node n>=1 is binary-heap index n (children 2n -> step 1,
// 2n+1 -> step 2). c(n) = #(step==1) = floor(log2 n) - popcount(n) + 1.
// n=0 is the sos position (path [-1]) -> source slot 88 for all heads.
// Chunks of 8 positions sharing one c; each maps block = (chunk, head): loads the
// 16 KB source ONCE, stores to 8 positions. Read traffic 268 MB -> 34 MB.
#define CMAX 272
struct Meta {
  int src[CMAX];
  int pos[CMAX][8];
  int n;
};
constexpr Meta build_meta() {
  Meta mt{};
  int cn[NPOS] = {};
  cn[0] = 11;  // sos marker
  for (int v = 1; v < NPOS; ++v) {
    int lg = 0;
    while ((1 << (lg + 1)) <= v) ++lg;
    int pc = 0;
    for (int b = 0; b < 12; ++b) pc += (v >> b) & 1;
    cn[v] = lg - pc + 1;  // in [0,10]
  }
  mt.n = 0;
  for (int c = 0; c <= 11; ++c) {
    int cur = -1;
    int cnt = 0;
    for (int v = 0; v < NPOS; ++v) {
      if (cn[v] != c) continue;
      if ((cnt & 7) == 0) {
        cur = mt.n++;
        mt.src[cur] = c;
        for (int i = 0; i < 8; ++i) mt.pos[cur][i] = -1;
      }
      mt.pos[cur][cnt & 7] = v;
      ++cnt;
    }
  }
  return mt;
}
__constant__ Meta META = build_meta();
constexpr int NCHUNKS = build_meta().n;  // <= 268

// Launch 1 (verbatim R4, verified): blocks [0,89): powers[b] = expm(k*A);
// blocks [89, 89+4096): steps 32x32 tiles (packed-bits compare). Steps blocks
// ride on the CUs the 89 expm blocks leave idle.
__global__ __launch_bounds__(256, 1) void pre_kernel(const float* __restrict__ U,
                                                     float* __restrict__ powers,
                                                     const int* __restrict__ pw, int L,
                                                     float* __restrict__ out_steps) {
  __shared__ __align__(16) float b0[4096];
  __shared__ __align__(16) float b1[4096];
  __shared__ __align__(16) float b2[4096];
  __shared__ __align__(16) float b3[4096];
  const int t = threadIdx.x;
  const int b = blockIdx.x;

  if (b >= 89) {  // ---- steps tile ----
    const int tb = b - 89;
    const int bi = (tb >> 6) * 32, bj = (tb & 63) * 32;
    unsigned long long* pki = reinterpret_cast<unsigned long long*>(b0);  // 32
    unsigned long long* pkj = pki + 32;                                   // 32
    int* li = reinterpret_cast<int*>(pkj + 32);                           // 32
    int* lj = li + 32;                                                    // 32
    if (t < 64) {
      const int r = (t < 32) ? (bi + t) : (bj + (t - 32));
      const int* row = pw + (size_t)r * L;
      int len = 0;
      unsigned long long packed = 0ull;
      for (int s = 0; s < L; ++s) {
        const int w = row[s];
        len += (w != PADW) ? 1 : 0;
        packed |= (unsigned long long)(unsigned)(w + 1) << (3 * s);  // w+1 in [0,4]
      }
      if (t < 32) {
        pki[t] = packed;
        li[t] = len;
      } else {
        pkj[t - 32] = packed;
        lj[t - 32] = len;
      }
    }
    __syncthreads();
    const int tx = t & 31, ty0 = t >> 5;
    const unsigned long long xj = pkj[tx];
    const int lenj = lj[tx];
#pragma unroll
    for (int m = 0; m < 4; ++m) {
      const int ty = ty0 + 8 * m;
      const unsigned long long x = pki[ty] ^ xj;
      const int leni = li[ty];
      const int p = x ? (__builtin_ctzll(x) / 3) : L;
      const int common = min(p, min(leni, lenj));
      const float steps = (float)(max(leni, lenj) - common);
      out_steps[(size_t)(bi + ty) * NPOS + (bj + tx)] = steps;
    }
    return;
  }

  // ---- expm block ----
  const bool sos = (b == 88);
  const int kp = sos ? 1 : (b >> 3);
  float* __restrict__ dst = powers + (size_t)b * 4096;

  if (kp == 0) {  // B^0 = I
    for (int i = t; i < 4096; i += 256) dst[i] = ((i >> 6) == (i & 63)) ? 1.0f : 0.0f;
    return;
  }

  const int m = sos ? 16 : (NHEADS + (b & 7));
  const float* __restrict__ Um = U + (size_t)m * 4096;
  const float scale = (float)kp * (1.0f / 256.0f);  // k/4 * 1/64

  const int r0 = ((t >> 4) & 15) << 2;  // tile rows r0..r0+3
  const int c0 = (t & 15) << 2;         // tile cols c0..c0+3

  // ---- P0: Ms = scale * (U - U^T) ----
  {
    f32x4 ur[4], uc[4];
#pragma unroll
    for (int i = 0; i < 4; ++i) ur[i] = ld4(&Um[(r0 + i) * 64 + c0]);
#pragma unroll
    for (int j = 0; j < 4; ++j) uc[j] = ld4(&Um[(c0 + j) * 64 + r0]);
#pragma unroll
    for (int i = 0; i < 4; ++i) {
      f32x4 v;
#pragma unroll
      for (int j = 0; j < 4; ++j) v[j] = scale * (ur[i][j] - uc[j][i]);
      st4(&b0[(r0 + i) * 64 + c0], v);
    }
  }
  __syncthreads();

  // ---- P1: M2 = -(Ms^T Ms) ----
  {
    float a[4][4];
    tzero(a);
#pragma unroll 4
    for (int k = 0; k < 64; ++k) tfma(a, ld4(&b0[k * 64 + r0]), ld4(&b0[k * 64 + c0]));
#pragma unroll
    for (int i = 0; i < 4; ++i) {
      f32x4 v;
#pragma unroll
      for (int j = 0; j < 4; ++j) v[j] = -a[i][j];
      st4(&b1[(r0 + i) * 64 + c0], v);
    }
  }
  __syncthreads();

  // ---- P23 (fused): M3 = -(Ms^T M2), M4 = (M2^T M2) ----
  {
    float a3[4][4], a4[4][4];
    tzero(a3);
    tzero(a4);
#pragma unroll 4
    for (int k = 0; k < 64; ++k) {
      const f32x4 msr = ld4(&b0[k * 64 + r0]);
      const f32x4 m2r = ld4(&b1[k * 64 + r0]);
      const f32x4 m2c = ld4(&b1[k * 64 + c0]);
      tfma(a3, msr, m2c);
      tfma(a4, m2r, m2c);
    }
#pragma unroll
    for (int i = 0; i < 4; ++i) {
      f32x4 v3, v4;
#pragma unroll
      for (int j = 0; j < 4; ++j) {
        v3[j] = -a3[i][j];
        v4[j] = a4[i][j];
      }
      st4(&b2[(r0 + i) * 64 + c0], v3);
      st4(&b3[(r0 + i) * 64 + c0], v4);
    }
  }
  __syncthreads();

  // ---- P4 (dual): E = low(M) + M^4*Q(M); Et = E(-M) = E^T ----
  {
    float aE[4][4], aO[4][4];
    tzero(aE);
    tzero(aO);
#pragma unroll 2
    for (int k = 0; k < 64; ++k) {
      const f32x4 xv = ld4(&b3[k * 64 + r0]);  // M4 row (M4^T = M4)
      const f32x4 msv = ld4(&b0[k * 64 + c0]);
      const f32x4 m2v = ld4(&b1[k * 64 + c0]);
      const f32x4 m3v = ld4(&b2[k * 64 + c0]);
      const f32x4 m4v = ld4(&b3[k * 64 + c0]);
      f32x4 ev, ov, yv, yw;
#pragma unroll
      for (int j = 0; j < 4; ++j) {
        ev[j] = fmaf(C8, m4v[j], C6 * m2v[j]);
        ov[j] = fmaf(C7, m3v[j], C5 * msv[j]);
        yv[j] = ev[j] + ov[j];
        yw[j] = ev[j] - ov[j];
      }
      tfma(aE, xv, yv);
      tfma(aO, xv, yw);
    }
    float eT[4][4], oT[4][4];
#pragma unroll
    for (int i = 0; i < 4; ++i) {
      const f32x4 msr = ld4(&b0[(r0 + i) * 64 + c0]);
      const f32x4 m2r = ld4(&b1[(r0 + i) * 64 + c0]);
      const f32x4 m3r = ld4(&b2[(r0 + i) * 64 + c0]);
      const f32x4 m4r = ld4(&b3[(r0 + i) * 64 + c0]);
#pragma unroll
      for (int j = 0; j < 4; ++j) {
        const float d = (r0 + i == c0 + j) ? 1.0f : 0.0f;
        const float even = d + fmaf(C4, m4r[j], C2 * m2r[j]);
        const float odd = fmaf(C3, m3r[j], C1 * msr[j]);
        eT[i][j] = aE[i][j] + even + odd;
        oT[i][j] = aO[i][j] + even - odd;
      }
    }
    __syncthreads();  // all reads of b0..b3 done
#pragma unroll
    for (int i = 0; i < 4; ++i) {
      f32x4 ve, vo;
#pragma unroll
      for (int j = 0; j < 4; ++j) {
        ve[j] = eT[i][j];
        vo[j] = oT[i][j];
      }
      st4(&b0[(r0 + i) * 64 + c0], ve);  // E
      st4(&b1[(r0 + i) * 64 + c0], vo);  // Et
    }
  }
  __syncthreads();

  // ---- P5 (fused): E2 = prim(Et,E); E2t = prim(E,Et) ----
  {
    float aA[4][4], aB[4][4];
    tzero(aA);
    tzero(aB);
#pragma unroll 2
    for (int k = 0; k < 64; ++k) {
      const f32x4 etr = ld4(&b1[k * 64 + r0]);
      const f32x4 er = ld4(&b0[k * 64 + r0]);
      const f32x4 ec = ld4(&b0[k * 64 + c0]);
      const f32x4 etc2 = ld4(&b1[k * 64 + c0]);
      tfma(aA, etr, ec);
      tfma(aB, er, etc2);
    }
#pragma unroll
    for (int i = 0; i < 4; ++i) {
      f32x4 va, vb;
#pragma unroll
      for (int j = 0; j < 4; ++j) {
        va[j] = aA[i][j];
        vb[j] = aB[i][j];
      }
      st4(&b2[(r0 + i) * 64 + c0], va);  // E2
      st4(&b3[(r0 + i) * 64 + c0], vb);  // E2t
    }
  }
  __syncthreads();

  // ---- P6: E4 = prim(E2t,E2) -> global ----
  {
    float a[4][4];
    tzero(a);
#pragma unroll 4
    for (int k = 0; k < 64; ++k) tfma(a, ld4(&b3[k * 64 + r0]), ld4(&b2[k * 64 + c0]));
#pragma unroll
    for (int i = 0; i < 4; ++i) {
      f32x4 v;
#pragma unroll
      for (int j = 0; j < 4; ++j) v[j] = a[i][j];
      st4(&dst[(r0 + i) * 64 + c0], v);
    }
  }
}

// Launch 2: grouped maps. Block = (chunk, head). Loads its 16 KB source ONCE
// (4 f32x4/thread from L2-hot powers), stores to up to 8 positions (32
// independent f32x4 stores/thread). Read traffic 268 MB -> 34 MB, so the write
// stream no longer competes with an equal-size read stream in L2.
__global__ __launch_bounds__(256) void maps_kernel(const float* __restrict__ powers,
                                                   float* __restrict__ out_maps) {
  const int chunk = blockIdx.x >> 3;
  const int h = blockIdx.x & 7;
  const int t = threadIdx.x;
  const int c = META.src[chunk];  // wave-uniform -> scalar load
  const float* src = powers + (size_t)((c == 11) ? 88 : c * NHEADS + h) * 4096;
  const f32x4* s4 = reinterpret_cast<const f32x4*>(src);
  const f32x4 v0 = s4[t];
  const f32x4 v1 = s4[t + 256];
  const f32x4 v2 = s4[t + 512];
  const f32x4 v3 = s4[t + 768];
#pragma unroll
  for (int p = 0; p < 8; ++p) {
    const int n = META.pos[chunk][p];
    if (n < 0) continue;
    f32x4* d4 = reinterpret_cast<f32x4*>(out_maps + ((size_t)n * NHEADS + h) * 4096);
    d4[t] = v0;
    d4[t + 256] = v1;
    d4[t + 512] = v2;
    d4[t + 768] = v3;
  }
}

extern "C" void kernel_launch(void* const* d_in, const int* in_sizes, int n_in,
                              void* d_out, int out_size, void* d_ws, size_t ws_size,
                              hipStream_t stream) {
  const float* U = (const float*)d_in[0];
  const int* pw = (const int*)d_in[1];
  const int L = in_sizes[1] / NPOS;  // = 10

  float* powers = (float*)d_ws;  // 89 * 4096 floats: [k*8+h] for k<=10, slot 88 = sos

  float* out_maps = (float*)d_out;
  float* out_steps = out_maps + (size_t)NPOS * NHEADS * 4096;

  hipLaunchKernelGGL(pre_kernel, dim3(89 + 64 * 64), dim3(256), 0, stream, U, powers,
                     pw, L, out_steps);
  hipLaunchKernelGGL(maps_kernel, dim3(NCHUNKS * 8), dim3(256), 0, stream, powers,
                     out_maps);
}